// Round 2
// baseline (405.041 us; speedup 1.0000x reference)
//
#include <hip/hip_runtime.h>
#include <hip/hip_bf16.h>
#include <math.h>

#define NN 20000
#define NE 320000
#define C0I 32
#define C1I 16
#define C0O 64
#define C1O 16
#define EPSF 1e-8f
#define STAGE_TOTAL 1671264

using bf16 = __hip_bfloat16;

__device__ __forceinline__ float b2f(bf16 v) { return __bfloat162float(v); }

// Order-preserving bijection float -> uint32 (monotone: a<b <=> fenc(a)<fenc(b)).
__device__ __forceinline__ unsigned fenc(float x) {
    unsigned b = __float_as_uint(x);
    return (b & 0x80000000u) ? ~b : (b | 0x80000000u);
}
__device__ __forceinline__ float fdec(unsigned k) {
    unsigned b = (k & 0x80000000u) ? (k & 0x7FFFFFFFu) : ~k;
    return __uint_as_float(b);
}

// ---- kd: dtype detector. Under "inputs are f32", even bf16 indices are f32
// mantissa halves: random exponents -> huge/NaN values. Under "inputs are bf16",
// they are N(0,1) data. flag=1 -> f32 inputs. ----
__global__ __launch_bounds__(256) void se3_detect(const void* x0raw, int* flag) {
    __shared__ int s;
    if (threadIdx.x == 0) s = 0;
    __syncthreads();
    const bf16* p = (const bf16*)x0raw;
    bool junk = false;
    for (int i = threadIdx.x * 2; i < 16384; i += 512) {
        float v = b2f(p[i]);
        if (!(fabsf(v) < 1e3f)) junk = true;   // catches huge AND NaN
    }
    if (junk) atomicOr(&s, 1);
    __syncthreads();
    if (threadIdx.x == 0) *flag = s;
}

// ---- kc: stage all 12 float inputs as f32 into ws (single downstream path) ----
__global__ __launch_bounds__(256) void se3_convert(
    const void* s0, const void* s1, const void* s2, const void* s3,
    const void* s4, const void* s5, const void* s6, const void* s7,
    const void* s8, const void* s9, const void* s10, const void* s11,
    const int* __restrict__ flag, float* __restrict__ dst) {
    const void* srcs[12] = {s0,s1,s2,s3,s4,s5,s6,s7,s8,s9,s10,s11};
    const int cnt[12] = {640000,960000,60000,2048,2048,1024,2048,1024,512,256,2048,256};
    int isf32 = *flag;
    for (int i = blockIdx.x * 256 + threadIdx.x; i < STAGE_TOTAL; i += gridDim.x * 256) {
        int seg = 0, off = i;
        while (off >= cnt[seg]) { off -= cnt[seg]; ++seg; }
        dst[i] = isf32 ? ((const float*)srcs[seg])[off]
                       : b2f(((const bf16*)srcs[seg])[off]);
    }
}

// ---- k0: Wqk0 = Wq0 @ Wk00^T [32x32], Wqk1 = Wq0 @ Wk10^T [32x16] ----
__global__ void se3_k0_combine(const float* __restrict__ Wq0, const float* __restrict__ Wk00,
                               const float* __restrict__ Wk10,
                               float* __restrict__ Wqk0, float* __restrict__ Wqk1) {
    int i = blockIdx.x * blockDim.x + threadIdx.x;
    if (i < C0I * C0I) {
        int cp = i >> 5, c = i & 31;
        float acc = 0.f;
        for (int j = 0; j < C0O; ++j) acc += Wq0[cp * C0O + j] * Wk00[c * C0O + j];
        Wqk0[i] = acc;
    } else if (i < C0I * C0I + C0I * C1I) {
        int t = i - C0I * C0I;
        int cp = t >> 4, c = t & 15;
        float acc = 0.f;
        for (int j = 0; j < C0O; ++j) acc += Wq0[cp * C0O + j] * Wk10[c * C0O + j];
        Wqk1[t] = acc;
    }
}

// ---- k1: per-node (one wave each): self terms into accumulators, qW0/qW1, init m/z ----
__global__ __launch_bounds__(256) void se3_k1_node(
    const float* __restrict__ x0, const float* __restrict__ x1,
    const float* __restrict__ Wqk0g, const float* __restrict__ Wqk1g,
    const float* __restrict__ Wself0, const float* __restrict__ Wself1,
    float* __restrict__ acc0, float* __restrict__ acc1,
    float* __restrict__ qW0, float* __restrict__ qW1,
    unsigned* __restrict__ mkey, float* __restrict__ z) {
    __shared__ float sQK0[C0I][C0I];
    __shared__ float sQK1[C0I][C1I];
    __shared__ float sWs0[C0I][C0O];
    __shared__ float sWs1[C1I][C1O];
    int tid = threadIdx.x;
    for (int i = tid; i < C0I * C0I; i += 256) sQK0[i >> 5][i & 31] = Wqk0g[i];
    for (int i = tid; i < C0I * C1I; i += 256) sQK1[i >> 4][i & 15] = Wqk1g[i];
    for (int i = tid; i < C0I * C0O; i += 256) sWs0[i >> 6][i & 63] = Wself0[i];
    for (int i = tid; i < C1I * C1O; i += 256) sWs1[i >> 4][i & 15] = Wself1[i];
    __syncthreads();

    int w = tid >> 6, lane = tid & 63;
    for (int n = blockIdx.x * 4 + w; n < NN; n += gridDim.x * 4) {
        const float* x0n = x0 + n * C0I;
        float accS = 0.f;
        for (int c = 0; c < C0I; ++c) accS += x0n[c] * sWs0[c][lane];
        acc0[n * C0O + lane] = accS;
        if (lane < C0I) {
            float a = 0.f;
            for (int c = 0; c < C0I; ++c) a += x0n[c] * sQK0[c][lane];
            qW0[n * C0I + lane] = a;
        } else if (lane < C0I + C1I) {
            int cc = lane - C0I;
            float a = 0.f;
            for (int c = 0; c < C0I; ++c) a += x0n[c] * sQK1[c][cc];
            qW1[n * C1I + cc] = a;
        }
        int f = lane >> 2, d3 = lane & 3;
        if (d3 < 3) {
            const float* x1n = x1 + n * C1I * 3;
            float a = 0.f;
            for (int c = 0; c < C1I; ++c) a += x1n[c * 3 + d3] * sWs1[c][f];
            acc1[n * (C1O * 3) + f * 3 + d3] = a;
        }
        if (lane == 0) { mkey[n] = fenc(-INFINITY); z[n] = 0.f; }
    }
}

// ---- k2: per-edge logits + segment max via order-preserving atomicMax ----
__global__ __launch_bounds__(256) void se3_k2_logits(
    const float* __restrict__ x0, const float* __restrict__ x1,
    const float* __restrict__ pos, const int* __restrict__ ei,
    const float* __restrict__ qW0, const float* __restrict__ qW1,
    float* __restrict__ lg, unsigned* __restrict__ mkey) {
    int e = blockIdx.x * 256 + threadIdx.x;
    if (e >= NE) return;
    int s = ei[e], d = ei[NE + e];
    float rx = pos[d * 3 + 0] - pos[s * 3 + 0];
    float ry = pos[d * 3 + 1] - pos[s * 3 + 1];
    float rz = pos[d * 3 + 2] - pos[s * 3 + 2];
    float inv = 1.f / (sqrtf(rx * rx + ry * ry + rz * rz) + EPSF);
    float Yx = rx * inv, Yy = ry * inv, Yz = rz * inv;

    const float* x0s = x0 + s * C0I;
    const float* q0 = qW0 + d * C0I;
    float acc = 0.f;
    for (int c = 0; c < C0I; ++c) acc += x0s[c] * q0[c];
    const float* x1s = x1 + s * C1I * 3;
    const float* q1 = qW1 + d * C1I;
    for (int c = 0; c < C1I; ++c) {
        float xd = x1s[c * 3 + 0] * Yx + x1s[c * 3 + 1] * Yy + x1s[c * 3 + 2] * Yz;
        acc += xd * q1[c];
    }
    acc *= 0.125f;
    lg[e] = acc;
    atomicMax(&mkey[d], fenc(acc));
}

// ---- k3: exp + segment sum ----
__global__ __launch_bounds__(256) void se3_k3_expsum(
    const int* __restrict__ ei, const unsigned* __restrict__ mkey,
    float* __restrict__ lg, float* __restrict__ z) {
    int e = blockIdx.x * 256 + threadIdx.x;
    if (e >= NE) return;
    int d = ei[NE + e];
    float ev = expf(lg[e] - fdec(mkey[d]));
    lg[e] = ev;
    atomicAdd(&z[d], ev);
}

// ---- k4: value messages + attention-weighted scatter (one wave per edge) ----
__global__ __launch_bounds__(256) void se3_k4_agg(
    const float* __restrict__ x0, const float* __restrict__ x1,
    const float* __restrict__ pos, const int* __restrict__ ei,
    const float* __restrict__ Wv00, const float* __restrict__ Wv10,
    const float* __restrict__ Wv01, const float* __restrict__ Wv11,
    const float* __restrict__ lg, const float* __restrict__ z,
    float* __restrict__ acc0g, float* __restrict__ acc1g) {
    __shared__ float sV00[C0I][C0O];
    __shared__ float sV10[C1I][C0O];
    __shared__ float sV01[C0I][C1O];
    __shared__ float sV11[C1I][C1O];
    int tid = threadIdx.x;
    for (int i = tid; i < C0I * C0O; i += 256) sV00[i >> 6][i & 63] = Wv00[i];
    for (int i = tid; i < C1I * C0O; i += 256) sV10[i >> 6][i & 63] = Wv10[i];
    for (int i = tid; i < C0I * C1O; i += 256) sV01[i >> 4][i & 15] = Wv01[i];
    for (int i = tid; i < C1I * C1O; i += 256) sV11[i >> 4][i & 15] = Wv11[i];
    __syncthreads();

    int w = tid >> 6, lane = tid & 63;
    int f = lane >> 2, d3 = lane & 3;
    int totalWaves = gridDim.x * 4;
    for (int e = blockIdx.x * 4 + w; e < NE; e += totalWaves) {
        int s = ei[e], d = ei[NE + e];
        float alpha = lg[e] / (z[d] + EPSF);
        float rx = pos[d * 3 + 0] - pos[s * 3 + 0];
        float ry = pos[d * 3 + 1] - pos[s * 3 + 1];
        float rz = pos[d * 3 + 2] - pos[s * 3 + 2];
        float inv = 1.f / (sqrtf(rx * rx + ry * ry + rz * rz) + EPSF);
        float Yx = rx * inv, Yy = ry * inv, Yz = rz * inv;

        const float* x0s = x0 + s * C0I;
        const float* x1s = x1 + s * C1I * 3;
        float a0 = 0.f, a01 = 0.f, a1 = 0.f;
        for (int c = 0; c < C0I; ++c) {
            float xc = x0s[c];
            a0  += xc * sV00[c][lane];
            a01 += xc * sV01[c][f];
        }
        for (int c = 0; c < C1I; ++c) {
            float xa = x1s[c * 3 + 0];
            float xb = x1s[c * 3 + 1];
            float xc = x1s[c * 3 + 2];
            float xd = xa * Yx + xb * Yy + xc * Yz;
            a0 += xd * sV10[c][lane];
            float comp = (d3 == 0) ? xa : ((d3 == 1) ? xb : xc);
            a1 += comp * sV11[c][f];
        }
        atomicAdd(&acc0g[d * C0O + lane], alpha * a0);
        if (d3 < 3) {
            float Yd = (d3 == 0) ? Yx : ((d3 == 1) ? Yy : Yz);
            atomicAdd(&acc1g[d * (C1O * 3) + f * 3 + d3], alpha * (a1 + a01 * Yd));
        }
    }
}

// ---- k5: f32 accumulators -> output (dtype per flag) ----
__global__ __launch_bounds__(256) void se3_k5_cast(
    const float* __restrict__ a, void* __restrict__ o,
    const int* __restrict__ flag, int n) {
    int i = blockIdx.x * 256 + threadIdx.x;
    if (i >= n) return;
    float v = a[i];
    if (*flag) ((float*)o)[i] = v;
    else       ((bf16*)o)[i] = __float2bfloat16(v);
}

extern "C" void kernel_launch(void* const* d_in, const int* in_sizes, int n_in,
                              void* d_out, int out_size, void* d_ws, size_t ws_size,
                              hipStream_t stream) {
    const void* x0r  = d_in[0];
    const void* x1r  = d_in[1];
    const void* posr = d_in[2];
    const int*  ei   = (const int*)d_in[3];

    int* flag   = (int*)d_ws;
    float* ws   = (float*)d_ws + 16;
    float* x0f  = ws;                         // 640000
    float* x1f  = x0f + 640000;               // 960000
    float* posf = x1f + 960000;               // 60000
    float* wq0    = posf + 60000;             // 2048
    float* wk00   = wq0 + 2048;
    float* wk10   = wk00 + 2048;              // 1024
    float* wv00   = wk10 + 1024;              // 2048
    float* wv10   = wv00 + 2048;              // 1024
    float* wv01   = wv10 + 1024;              // 512
    float* wv11   = wv01 + 512;               // 256
    float* wself0 = wv11 + 256;               // 2048
    float* wself1 = wself0 + 2048;            // 256
    float* Wqk0 = ws + STAGE_TOTAL;           // 1024
    float* Wqk1 = Wqk0 + 1024;                // 512
    float* qW0  = Wqk1 + 512;                 // NN*32
    float* qW1  = qW0 + (size_t)NN * C0I;     // NN*16
    unsigned* mkey = (unsigned*)(qW1 + (size_t)NN * C1I); // NN
    float* z    = (float*)(mkey + NN);        // NN
    float* lg   = z + NN;                     // NE
    float* acc0 = lg + NE;                    // NN*64
    float* acc1 = acc0 + (size_t)NN * C0O;    // NN*48 (contiguous after acc0)

    se3_detect<<<1, 256, 0, stream>>>(x0r, flag);
    se3_convert<<<2048, 256, 0, stream>>>(x0r, x1r, posr,
        d_in[4], d_in[5], d_in[6], d_in[7], d_in[8], d_in[9], d_in[10], d_in[11], d_in[12],
        flag, ws);
    se3_k0_combine<<<6, 256, 0, stream>>>(wq0, wk00, wk10, Wqk0, Wqk1);
    se3_k1_node<<<1250, 256, 0, stream>>>(x0f, x1f, Wqk0, Wqk1, wself0, wself1,
                                          acc0, acc1, qW0, qW1, mkey, z);
    se3_k2_logits<<<(NE + 255) / 256, 256, 0, stream>>>(x0f, x1f, posf, ei, qW0, qW1, lg, mkey);
    se3_k3_expsum<<<(NE + 255) / 256, 256, 0, stream>>>(ei, mkey, lg, z);
    se3_k4_agg<<<2048, 256, 0, stream>>>(x0f, x1f, posf, ei, wv00, wv10, wv01, wv11,
                                         lg, z, acc0, acc1);
    int ntot = NN * (C0O + C1O * 3);
    se3_k5_cast<<<(ntot + 255) / 256, 256, 0, stream>>>(acc0, d_out, flag, ntot);
}